// Round 6
// baseline (462.513 us; speedup 1.0000x reference)
//
#include <hip/hip_runtime.h>
#include <math.h>

// GCN: 7 graph-conv layers. N=65536 nodes, E=1048576 edges, feat 128->64(x6)->40.
// dst-CSR once per call; per layer {register-blocked GEMM -> bf16 support,
// pull-aggregate: wave-uniform edge list (SGPR), 2 edges/gather, f32 accum}.

constexpr int NFEAT = 128, NHID = 64, NCLASS = 40;

typedef unsigned short ushort_t;

__device__ inline float bf2f(ushort_t u) {
  union { unsigned int i; float f; } v; v.i = ((unsigned int)u) << 16; return v.f;
}
__device__ inline ushort_t f2bf(float f) {  // round-to-nearest-even
  union { float f; unsigned int i; } v; v.f = f;
  unsigned int lsb = (v.i >> 16) & 1u;
  v.i += 0x7fffu + lsb;
  return (ushort_t)(v.i >> 16);
}

// Histogram + per-edge rank; 4 independent atomics in flight per thread.
__global__ void rank_k(const int* __restrict__ dst, int* __restrict__ cnt,
                       int* __restrict__ rank, int E) {
  int i = blockIdx.x * blockDim.x + threadIdx.x;
  int stride = gridDim.x * blockDim.x;
#pragma unroll
  for (int j = 0; j < 4; ++j) {
    int idx = i + j * stride;
    if (idx < E) rank[idx] = atomicAdd(&cnt[dst[idx]], 1);
  }
}

__global__ void scan1_k(const int* __restrict__ cnt, int* __restrict__ off,
                        int* __restrict__ bsum, int n) {
  __shared__ int tmp[256];
  int tid = threadIdx.x;
  int i = blockIdx.x * 256 + tid;
  int v = (i < n) ? cnt[i] : 0;
  tmp[tid] = v;
  __syncthreads();
  for (int d = 1; d < 256; d <<= 1) {
    int t = (tid >= d) ? tmp[tid - d] : 0;
    __syncthreads();
    tmp[tid] += t;
    __syncthreads();
  }
  if (i < n) off[i] = tmp[tid] - v;  // exclusive
  if (tid == 255) bsum[blockIdx.x] = tmp[255];
}

__global__ void scan2_k(int* __restrict__ bsum, int nb) {
  __shared__ int tmp[256];
  int tid = threadIdx.x;
  int v = (tid < nb) ? bsum[tid] : 0;
  tmp[tid] = v;
  __syncthreads();
  for (int d = 1; d < 256; d <<= 1) {
    int t = (tid >= d) ? tmp[tid - d] : 0;
    __syncthreads();
    tmp[tid] += t;
    __syncthreads();
  }
  if (tid < nb) bsum[tid] = tmp[tid] - v;  // exclusive
}

__global__ void scan3_k(int* __restrict__ off, const int* __restrict__ bsum, int n, int E) {
  int i = blockIdx.x * blockDim.x + threadIdx.x;
  if (i < n) off[i] += bsum[i >> 8];
  if (i == 0) off[n] = E;
}

// Atomic-free scatter: pos = off[dst] + rank, non-temporal 8B store.
__global__ void fill_k(const int* __restrict__ src, const int* __restrict__ dst,
                       const float* __restrict__ w, const int* __restrict__ off,
                       const int* __restrict__ rank, int2* __restrict__ edata, int E) {
  int i = blockIdx.x * blockDim.x + threadIdx.x;
  if (i < E) {
    int pos = off[dst[i]] + rank[i];
    int2 v = make_int2(src[i], __float_as_int(w[i]));
    __builtin_nontemporal_store(*(const long long*)&v, (long long*)&edata[pos]);
  }
}

// Register-blocked GEMM: 64x64 tile / 256-thread block, 4x4 per thread.
// Output written as bf16 (support tables).
template<int FI, int FO>
__global__ __launch_bounds__(256) void gemm_k(const float* __restrict__ h,
                                              const float* __restrict__ W,
                                              ushort_t* __restrict__ out, int n) {
  constexpr int HS = 68;            // h_lds row stride, pad 4
  __shared__ float hl[64 * HS];     // 17408 B
  __shared__ float wl[64 * 64];     // 16384 B
  int tid = threadIdx.x;
  int row0 = blockIdx.x * 64;
  int tx = tid & 15, ty = tid >> 4;

  float acc[4][4] = {};

  for (int kc = 0; kc < FI; kc += 64) {
    {
      const float* hb = h + (size_t)row0 * FI + kc;
      for (int i = tid; i < 64 * 16; i += 256) {
        int r = i >> 4, kk = (i & 15) << 2;
        float4 v = *(const float4*)(hb + (size_t)r * FI + kk);
        *(float4*)&hl[r * HS + kk] = v;
      }
    }
    if (FO == 64) {
      const float4* Wb = (const float4*)(W + (size_t)kc * 64);
      for (int i = tid; i < 64 * 16; i += 256) ((float4*)wl)[i] = Wb[i];
    } else {
      for (int i = tid; i < 64 * 64; i += 256) wl[i] = 0.0f;
      __syncthreads();
      for (int i = tid; i < 64 * FO; i += 256)
        wl[(i / FO) * 64 + (i % FO)] = W[(size_t)(kc + i / FO) * FO + (i % FO)];
    }
    __syncthreads();

    for (int k4 = 0; k4 < 64; k4 += 4) {
      float4 a[4];
#pragma unroll
      for (int r = 0; r < 4; ++r)
        a[r] = *(const float4*)&hl[(ty * 4 + r) * HS + k4];
#pragma unroll
      for (int j = 0; j < 4; ++j) {
        float4 bv = *(const float4*)&wl[(k4 + j) * 64 + tx * 4];
        const float* bp = (const float*)&bv;
#pragma unroll
        for (int r = 0; r < 4; ++r) {
          const float* ap = (const float*)&a[r];
#pragma unroll
          for (int c = 0; c < 4; ++c) acc[r][c] += ap[j] * bp[c];
        }
      }
    }
    __syncthreads();
  }

  if (FO == 64) {
#pragma unroll
    for (int r = 0; r < 4; ++r) {
      ushort_t pk[4];
#pragma unroll
      for (int c = 0; c < 4; ++c) pk[c] = f2bf(acc[r][c]);
      *(ushort4*)&out[(size_t)(row0 + ty * 4 + r) * 64 + tx * 4] =
          make_ushort4(pk[0], pk[1], pk[2], pk[3]);
    }
  } else {
#pragma unroll
    for (int r = 0; r < 4; ++r)
#pragma unroll
      for (int c = 0; c < 4; ++c) {
        int col = tx * 4 + c;
        if (col < FO) out[(size_t)(row0 + ty * 4 + r) * FO + col] = f2bf(acc[r][c]);
      }
  }
}

// Pull aggregation: one wave per node. Lanes 0-31 = even edges, 32-63 = odd;
// lane loads 2 bf16 feats per gather -> 2 edges per gather instruction.
// e0/e1 are wave-uniform (readfirstlane -> SGPR); steady-state loop has
// compile-time edata offsets and no bounds checks; single masked tail iter.
__global__ void agg_k(const ushort_t* __restrict__ support,
                      const int2* __restrict__ edata,
                      const int* __restrict__ off,
                      const float* __restrict__ bias,
                      const float* __restrict__ resid,
                      float* __restrict__ out,
                      int n, int do_relu) {
  int tid = blockIdx.x * blockDim.x + threadIdx.x;
  int wid = tid >> 6, lane = tid & 63;
  if (wid >= n) return;
  int half = lane >> 5;   // which edge of the pair
  int hl   = lane & 31;   // feature pair (feats 2hl, 2hl+1)
  int e0 = __builtin_amdgcn_readfirstlane(off[wid]);
  int e1 = __builtin_amdgcn_readfirstlane(off[wid + 1]);
  int deg = e1 - e0;

  const ushort_t* sp = support + hl * 2;      // per-lane feature base
  const int2* ep = edata + e0 + half;         // uniform base + half

  float ax[8] = {}, ay[8] = {};
  int it = 0;
  // full 16-edge chunks: no clamps, consecutive uniform-offset edata loads
  for (; it + 16 <= deg; it += 16) {
    int2 ed[8];
#pragma unroll
    for (int j = 0; j < 8; ++j) ed[j] = ep[it + 2 * j];
    unsigned int u[8];
#pragma unroll
    for (int j = 0; j < 8; ++j)
      u[j] = *(const unsigned int*)(sp + ((size_t)ed[j].x << 6));
#pragma unroll
    for (int j = 0; j < 8; ++j) {
      float w = __int_as_float(ed[j].y);
      ax[j] += w * __int_as_float(u[j] << 16);
      ay[j] += w * __int_as_float(u[j] & 0xffff0000u);
    }
  }
  // masked tail (once): up to 15 remaining edges
  if (it < deg) {
    int2 ed[8];
    unsigned int u[8];
#pragma unroll
    for (int j = 0; j < 8; ++j) {
      int rel = it + 2 * j;                       // relative idx for this half
      int relc = rel < deg - half ? rel : 0;      // clamp to a valid slot
      ed[j] = ep[relc];
    }
#pragma unroll
    for (int j = 0; j < 8; ++j)
      u[j] = *(const unsigned int*)(sp + ((size_t)ed[j].x << 6));
#pragma unroll
    for (int j = 0; j < 8; ++j) {
      int rel = it + 2 * j;
      float w = (rel < deg - half) ? __int_as_float(ed[j].y) : 0.0f;
      ax[j] += w * __int_as_float(u[j] << 16);
      ay[j] += w * __int_as_float(u[j] & 0xffff0000u);
    }
  }
  float sx = ((ax[0] + ax[1]) + (ax[2] + ax[3])) + ((ax[4] + ax[5]) + (ax[6] + ax[7]));
  float sy = ((ay[0] + ay[1]) + (ay[2] + ay[3])) + ((ay[4] + ay[5]) + (ay[6] + ay[7]));
  sx += __shfl_xor(sx, 32, 64);
  sy += __shfl_xor(sy, 32, 64);
  if (half == 0) {
    float2 bv = *(const float2*)&bias[hl * 2];
    float vx = sx + bv.x, vy = sy + bv.y;
    if (do_relu) { vx = fmaxf(vx, 0.0f); vy = fmaxf(vy, 0.0f); }
    if (resid) {
      float2 r = *(const float2*)&resid[(size_t)wid * 64 + hl * 2];
      vx += r.x; vy += r.y;
    }
    *(float2*)&out[(size_t)wid * 64 + hl * 2] = make_float2(vx, vy);
  }
}

// Final layer: FO=40, same scheme (feat pairs 0..19 valid), then
// bias + log_softmax over 40 classes via 64-lane butterflies.
__global__ void agg_final_k(const ushort_t* __restrict__ support,
                            const int2* __restrict__ edata,
                            const int* __restrict__ off,
                            const float* __restrict__ bias,
                            float* __restrict__ out, int n) {
  int tid = blockIdx.x * blockDim.x + threadIdx.x;
  int wid = tid >> 6, lane = tid & 63;
  if (wid >= n) return;
  int half = lane >> 5;
  int hl   = lane & 31;
  int col  = (hl < 20 ? hl : 0) * 2;   // clamp to stay in-row
  int e0 = __builtin_amdgcn_readfirstlane(off[wid]);
  int e1 = __builtin_amdgcn_readfirstlane(off[wid + 1]);
  int deg = e1 - e0;

  const ushort_t* sp = support + col;
  const int2* ep = edata + e0 + half;

  float ax[8] = {}, ay[8] = {};
  int it = 0;
  for (; it + 16 <= deg; it += 16) {
    int2 ed[8];
#pragma unroll
    for (int j = 0; j < 8; ++j) ed[j] = ep[it + 2 * j];
    unsigned int u[8];
#pragma unroll
    for (int j = 0; j < 8; ++j)
      u[j] = *(const unsigned int*)(sp + (size_t)ed[j].x * NCLASS);
#pragma unroll
    for (int j = 0; j < 8; ++j) {
      float w = __int_as_float(ed[j].y);
      ax[j] += w * __int_as_float(u[j] << 16);
      ay[j] += w * __int_as_float(u[j] & 0xffff0000u);
    }
  }
  if (it < deg) {
    int2 ed[8];
    unsigned int u[8];
#pragma unroll
    for (int j = 0; j < 8; ++j) {
      int rel = it + 2 * j;
      int relc = rel < deg - half ? rel : 0;
      ed[j] = ep[relc];
    }
#pragma unroll
    for (int j = 0; j < 8; ++j)
      u[j] = *(const unsigned int*)(sp + (size_t)ed[j].x * NCLASS);
#pragma unroll
    for (int j = 0; j < 8; ++j) {
      int rel = it + 2 * j;
      float w = (rel < deg - half) ? __int_as_float(ed[j].y) : 0.0f;
      ax[j] += w * __int_as_float(u[j] << 16);
      ay[j] += w * __int_as_float(u[j] & 0xffff0000u);
    }
  }
  float sx = ((ax[0] + ax[1]) + (ax[2] + ax[3])) + ((ax[4] + ax[5]) + (ax[6] + ax[7]));
  float sy = ((ay[0] + ay[1]) + (ay[2] + ay[3])) + ((ay[4] + ay[5]) + (ay[6] + ay[7]));
  sx += __shfl_xor(sx, 32, 64);
  sy += __shfl_xor(sy, 32, 64);
  float2 bv = *(const float2*)&bias[col];
  float vx = sx + bv.x, vy = sy + bv.y;

  bool valid = (hl < 20);
  float m = valid ? fmaxf(vx, vy) : -INFINITY;
#pragma unroll
  for (int d = 32; d; d >>= 1) m = fmaxf(m, __shfl_xor(m, d, 64));
  float ex = valid ? (expf(vx - m) + expf(vy - m)) : 0.0f;
  float s = ex;
#pragma unroll
  for (int d = 32; d; d >>= 1) s += __shfl_xor(s, d, 64);
  float ls = logf(s);
  if (half == 0 && valid)
    *(float2*)&out[(size_t)wid * NCLASS + hl * 2] = make_float2(vx - m - ls, vy - m - ls);
}

extern "C" void kernel_launch(void* const* d_in, const int* in_sizes, int n_in,
                              void* d_out, int out_size, void* d_ws, size_t ws_size,
                              hipStream_t stream) {
  const float* x   = (const float*)d_in[0];
  const int*   src = (const int*)d_in[1];
  const int*   dst = (const int*)d_in[2];
  const float* ew  = (const float*)d_in[3];
  const float* W[7]; const float* b[7];
  for (int i = 0; i < 7; ++i) {
    W[i] = (const float*)d_in[4 + 2 * i];
    b[i] = (const float*)d_in[5 + 2 * i];
  }
  int N = in_sizes[0] / NFEAT;   // 65536
  int E = in_sizes[1];           // 1048576

  char* ws = (char*)d_ws;
  int*      off     = (int*)(ws + 0);                 // (N+1) ints
  int*      bsum    = (int*)(ws + (1ll << 20));       // 256 ints
  int*      cnt     = (int*)(ws + (2ll << 20));       // N ints
  int2*     edata   = (int2*)(ws + (4ll << 20));      // E int2 = 8MB  [4,12)
  int*      rank    = (int*)(ws + (12ll << 20));      // E ints = 4MB  [12,16)
  ushort_t* support = (ushort_t*)(ws + (16ll << 20)); // N*64 bf16 = 8MB [16,24)
  float*    hA      = (float*)(ws + (32ll << 20));    // 16MB
  float*    hB      = (float*)(ws + (48ll << 20));    // 16MB

  // ---- build dst-CSR ----
  hipMemsetAsync(cnt, 0, (size_t)N * sizeof(int), stream);
  rank_k<<<(E / 4 + 255) / 256, 256, 0, stream>>>(dst, cnt, rank, E);
  int nb = (N + 255) / 256;  // 256 blocks
  scan1_k<<<nb, 256, 0, stream>>>(cnt, off, bsum, N);
  scan2_k<<<1, 256, 0, stream>>>(bsum, nb);
  scan3_k<<<nb, 256, 0, stream>>>(off, bsum, N, E);
  fill_k<<<(E + 255) / 256, 256, 0, stream>>>(src, dst, ew, off, rank, edata, E);

  int gb_gemm = N / 64;  // 1024 blocks
  int gb_agg  = N / 4;   // 4 waves per 256-thread block

  // L1: x[128] -> 64, relu
  gemm_k<128, 64><<<gb_gemm, 256, 0, stream>>>(x, W[0], support, N);
  agg_k<<<gb_agg, 256, 0, stream>>>(support, edata, off, b[0], nullptr, hA, N, 1);
  // L2
  gemm_k<64, 64><<<gb_gemm, 256, 0, stream>>>(hA, W[1], support, N);
  agg_k<<<gb_agg, 256, 0, stream>>>(support, edata, off, b[1], nullptr, hB, N, 1);
  // L3: + residual (h2 = hB)
  gemm_k<64, 64><<<gb_gemm, 256, 0, stream>>>(hB, W[2], support, N);
  agg_k<<<gb_agg, 256, 0, stream>>>(support, edata, off, b[2], hB, hA, N, 1);
  // L4: + residual (h3 = hA)
  gemm_k<64, 64><<<gb_gemm, 256, 0, stream>>>(hA, W[3], support, N);
  agg_k<<<gb_agg, 256, 0, stream>>>(support, edata, off, b[3], hA, hB, N, 1);
  // L5: + residual (h4 = hB)
  gemm_k<64, 64><<<gb_gemm, 256, 0, stream>>>(hB, W[4], support, N);
  agg_k<<<gb_agg, 256, 0, stream>>>(support, edata, off, b[4], hB, hA, N, 1);
  // L6
  gemm_k<64, 64><<<gb_gemm, 256, 0, stream>>>(hA, W[5], support, N);
  agg_k<<<gb_agg, 256, 0, stream>>>(support, edata, off, b[5], nullptr, hB, N, 1);
  // L7: 64 -> 40, + log_softmax
  gemm_k<64, 40><<<gb_gemm, 256, 0, stream>>>(hB, W[6], support, N);
  agg_final_k<<<gb_agg, 256, 0, stream>>>(support, edata, off, b[6], (float*)d_out, N);
}

// Round 7
// 410.257 us; speedup vs baseline: 1.1274x; 1.1274x over previous
//
#include <hip/hip_runtime.h>
#include <math.h>

// GCN: 7 graph-conv layers. N=65536 nodes, E=1048576 edges, feat 128->64(x6)->40.
// dst-CSR once per call; per layer {register-blocked GEMM -> bf16 support,
// pull-aggregate: flat-issue 32-edge body (16 gathers in flight), f32 accum}.

constexpr int NFEAT = 128, NHID = 64, NCLASS = 40;

typedef unsigned short ushort_t;

__device__ inline float bf2f(ushort_t u) {
  union { unsigned int i; float f; } v; v.i = ((unsigned int)u) << 16; return v.f;
}
__device__ inline ushort_t f2bf(float f) {  // round-to-nearest-even
  union { float f; unsigned int i; } v; v.f = f;
  unsigned int lsb = (v.i >> 16) & 1u;
  v.i += 0x7fffu + lsb;
  return (ushort_t)(v.i >> 16);
}

// Histogram + per-edge rank; 4 independent atomics in flight per thread.
__global__ void rank_k(const int* __restrict__ dst, int* __restrict__ cnt,
                       int* __restrict__ rank, int E) {
  int i = blockIdx.x * blockDim.x + threadIdx.x;
  int stride = gridDim.x * blockDim.x;
#pragma unroll
  for (int j = 0; j < 4; ++j) {
    int idx = i + j * stride;
    if (idx < E) rank[idx] = atomicAdd(&cnt[dst[idx]], 1);
  }
}

__global__ void scan1_k(const int* __restrict__ cnt, int* __restrict__ off,
                        int* __restrict__ bsum, int n) {
  __shared__ int tmp[256];
  int tid = threadIdx.x;
  int i = blockIdx.x * 256 + tid;
  int v = (i < n) ? cnt[i] : 0;
  tmp[tid] = v;
  __syncthreads();
  for (int d = 1; d < 256; d <<= 1) {
    int t = (tid >= d) ? tmp[tid - d] : 0;
    __syncthreads();
    tmp[tid] += t;
    __syncthreads();
  }
  if (i < n) off[i] = tmp[tid] - v;  // exclusive
  if (tid == 255) bsum[blockIdx.x] = tmp[255];
}

__global__ void scan2_k(int* __restrict__ bsum, int nb) {
  __shared__ int tmp[256];
  int tid = threadIdx.x;
  int v = (tid < nb) ? bsum[tid] : 0;
  tmp[tid] = v;
  __syncthreads();
  for (int d = 1; d < 256; d <<= 1) {
    int t = (tid >= d) ? tmp[tid - d] : 0;
    __syncthreads();
    tmp[tid] += t;
    __syncthreads();
  }
  if (tid < nb) bsum[tid] = tmp[tid] - v;  // exclusive
}

__global__ void scan3_k(int* __restrict__ off, const int* __restrict__ bsum, int n, int E) {
  int i = blockIdx.x * blockDim.x + threadIdx.x;
  if (i < n) off[i] += bsum[i >> 8];
  if (i == 0) off[n] = E;
}

// Atomic-free scatter: pos = off[dst] + rank, non-temporal 8B store.
__global__ void fill_k(const int* __restrict__ src, const int* __restrict__ dst,
                       const float* __restrict__ w, const int* __restrict__ off,
                       const int* __restrict__ rank, int2* __restrict__ edata, int E) {
  int i = blockIdx.x * blockDim.x + threadIdx.x;
  if (i < E) {
    int pos = off[dst[i]] + rank[i];
    int2 v = make_int2(src[i], __float_as_int(w[i]));
    __builtin_nontemporal_store(*(const long long*)&v, (long long*)&edata[pos]);
  }
}

// Register-blocked GEMM: 64x64 tile / 256-thread block, 4x4 per thread.
// Output written as bf16 (support tables).
template<int FI, int FO>
__global__ __launch_bounds__(256) void gemm_k(const float* __restrict__ h,
                                              const float* __restrict__ W,
                                              ushort_t* __restrict__ out, int n) {
  constexpr int HS = 68;            // h_lds row stride, pad 4
  __shared__ float hl[64 * HS];     // 17408 B
  __shared__ float wl[64 * 64];     // 16384 B
  int tid = threadIdx.x;
  int row0 = blockIdx.x * 64;
  int tx = tid & 15, ty = tid >> 4;

  float acc[4][4] = {};

  for (int kc = 0; kc < FI; kc += 64) {
    {
      const float* hb = h + (size_t)row0 * FI + kc;
      for (int i = tid; i < 64 * 16; i += 256) {
        int r = i >> 4, kk = (i & 15) << 2;
        float4 v = *(const float4*)(hb + (size_t)r * FI + kk);
        *(float4*)&hl[r * HS + kk] = v;
      }
    }
    if (FO == 64) {
      const float4* Wb = (const float4*)(W + (size_t)kc * 64);
      for (int i = tid; i < 64 * 16; i += 256) ((float4*)wl)[i] = Wb[i];
    } else {
      for (int i = tid; i < 64 * 64; i += 256) wl[i] = 0.0f;
      __syncthreads();
      for (int i = tid; i < 64 * FO; i += 256)
        wl[(i / FO) * 64 + (i % FO)] = W[(size_t)(kc + i / FO) * FO + (i % FO)];
    }
    __syncthreads();

    for (int k4 = 0; k4 < 64; k4 += 4) {
      float4 a[4];
#pragma unroll
      for (int r = 0; r < 4; ++r)
        a[r] = *(const float4*)&hl[(ty * 4 + r) * HS + k4];
#pragma unroll
      for (int j = 0; j < 4; ++j) {
        float4 bv = *(const float4*)&wl[(k4 + j) * 64 + tx * 4];
        const float* bp = (const float*)&bv;
#pragma unroll
        for (int r = 0; r < 4; ++r) {
          const float* ap = (const float*)&a[r];
#pragma unroll
          for (int c = 0; c < 4; ++c) acc[r][c] += ap[j] * bp[c];
        }
      }
    }
    __syncthreads();
  }

  if (FO == 64) {
#pragma unroll
    for (int r = 0; r < 4; ++r) {
      ushort_t pk[4];
#pragma unroll
      for (int c = 0; c < 4; ++c) pk[c] = f2bf(acc[r][c]);
      *(ushort4*)&out[(size_t)(row0 + ty * 4 + r) * 64 + tx * 4] =
          make_ushort4(pk[0], pk[1], pk[2], pk[3]);
    }
  } else {
#pragma unroll
    for (int r = 0; r < 4; ++r)
#pragma unroll
      for (int c = 0; c < 4; ++c) {
        int col = tx * 4 + c;
        if (col < FO) out[(size_t)(row0 + ty * 4 + r) * FO + col] = f2bf(acc[r][c]);
      }
  }
}

// Pull aggregation: one wave per node. Lanes 0-31 = even edges, 32-63 = odd;
// lane loads 2 bf16 feats per gather. Flat-issue body: all 16 src loads, then
// all 16 gathers, then all 16 weight loads are in flight before any use ->
// one latency epoch covers up to 32 edges (99.98% of nodes at Poisson(16)).
__global__ __launch_bounds__(256, 8) void agg_k(
    const ushort_t* __restrict__ support,
    const int2* __restrict__ edata,
    const int* __restrict__ off,
    const float* __restrict__ bias,
    const float* __restrict__ resid,
    float* __restrict__ out,
    int n, int do_relu) {
  int tid = blockIdx.x * blockDim.x + threadIdx.x;
  int wid = tid >> 6, lane = tid & 63;
  if (wid >= n) return;
  int half = lane >> 5;   // which edge of the pair
  int hl   = lane & 31;   // feature pair (feats 2hl, 2hl+1)
  int e0 = __builtin_amdgcn_readfirstlane(off[wid]);
  int e1 = __builtin_amdgcn_readfirstlane(off[wid + 1]);
  int deg = e1 - e0;

  const ushort_t* sp = support + hl * 2;      // per-lane feature base
  const int* epi = (const int*)(edata + e0);  // int view of this node's edges

  float ax[4] = {}, ay[4] = {};
  if (deg > 0) {
    // ---- flat 32-edge body (masked) ----
    int sx[16];
#pragma unroll
    for (int j = 0; j < 16; ++j) {
      int rel = 2 * j + half;
      sx[j] = epi[(rel < deg ? rel : 0) * 2];          // src index
    }
    unsigned int u[16];
#pragma unroll
    for (int j = 0; j < 16; ++j)
      u[j] = *(const unsigned int*)(sp + ((size_t)sx[j] << 6));
    float wv[16];
#pragma unroll
    for (int j = 0; j < 16; ++j) {
      int rel = 2 * j + half;
      wv[j] = (rel < deg) ? __int_as_float(epi[rel * 2 + 1]) : 0.0f;
    }
#pragma unroll
    for (int j = 0; j < 16; ++j) {
      ax[j & 3] += wv[j] * __int_as_float(u[j] << 16);
      ay[j & 3] += wv[j] * __int_as_float(u[j] & 0xffff0000u);
    }
    // ---- rare remainder (deg > 32): masked 16-edge chunks ----
    for (int it = 32; it < deg; it += 16) {
      int2 ed[8];
#pragma unroll
      for (int j = 0; j < 8; ++j) {
        int rel = it + 2 * j + half;
        ed[j] = *(const int2*)(epi + (rel < deg ? rel : 0) * 2);
      }
      unsigned int uu[8];
#pragma unroll
      for (int j = 0; j < 8; ++j)
        uu[j] = *(const unsigned int*)(sp + ((size_t)ed[j].x << 6));
#pragma unroll
      for (int j = 0; j < 8; ++j) {
        int rel = it + 2 * j + half;
        float w = (rel < deg) ? __int_as_float(ed[j].y) : 0.0f;
        ax[j & 3] += w * __int_as_float(uu[j] << 16);
        ay[j & 3] += w * __int_as_float(uu[j] & 0xffff0000u);
      }
    }
  }
  float sx2 = (ax[0] + ax[1]) + (ax[2] + ax[3]);
  float sy2 = (ay[0] + ay[1]) + (ay[2] + ay[3]);
  sx2 += __shfl_xor(sx2, 32, 64);
  sy2 += __shfl_xor(sy2, 32, 64);
  if (half == 0) {
    float2 bv = *(const float2*)&bias[hl * 2];
    float vx = sx2 + bv.x, vy = sy2 + bv.y;
    if (do_relu) { vx = fmaxf(vx, 0.0f); vy = fmaxf(vy, 0.0f); }
    if (resid) {
      float2 r = *(const float2*)&resid[(size_t)wid * 64 + hl * 2];
      vx += r.x; vy += r.y;
    }
    *(float2*)&out[(size_t)wid * 64 + hl * 2] = make_float2(vx, vy);
  }
}

// Final layer: FO=40, same flat-issue scheme (feat pairs 0..19 valid), then
// bias + log_softmax over 40 classes via 64-lane butterflies.
__global__ __launch_bounds__(256, 8) void agg_final_k(
    const ushort_t* __restrict__ support,
    const int2* __restrict__ edata,
    const int* __restrict__ off,
    const float* __restrict__ bias,
    float* __restrict__ out, int n) {
  int tid = blockIdx.x * blockDim.x + threadIdx.x;
  int wid = tid >> 6, lane = tid & 63;
  if (wid >= n) return;
  int half = lane >> 5;
  int hl   = lane & 31;
  int col  = (hl < 20 ? hl : 0) * 2;   // clamp to stay in-row
  int e0 = __builtin_amdgcn_readfirstlane(off[wid]);
  int e1 = __builtin_amdgcn_readfirstlane(off[wid + 1]);
  int deg = e1 - e0;

  const ushort_t* sp = support + col;
  const int* epi = (const int*)(edata + e0);

  float ax[4] = {}, ay[4] = {};
  if (deg > 0) {
    int sx[16];
#pragma unroll
    for (int j = 0; j < 16; ++j) {
      int rel = 2 * j + half;
      sx[j] = epi[(rel < deg ? rel : 0) * 2];
    }
    unsigned int u[16];
#pragma unroll
    for (int j = 0; j < 16; ++j)
      u[j] = *(const unsigned int*)(sp + (size_t)sx[j] * NCLASS);
    float wv[16];
#pragma unroll
    for (int j = 0; j < 16; ++j) {
      int rel = 2 * j + half;
      wv[j] = (rel < deg) ? __int_as_float(epi[rel * 2 + 1]) : 0.0f;
    }
#pragma unroll
    for (int j = 0; j < 16; ++j) {
      ax[j & 3] += wv[j] * __int_as_float(u[j] << 16);
      ay[j & 3] += wv[j] * __int_as_float(u[j] & 0xffff0000u);
    }
    for (int it = 32; it < deg; it += 16) {
      int2 ed[8];
#pragma unroll
      for (int j = 0; j < 8; ++j) {
        int rel = it + 2 * j + half;
        ed[j] = *(const int2*)(epi + (rel < deg ? rel : 0) * 2);
      }
      unsigned int uu[8];
#pragma unroll
      for (int j = 0; j < 8; ++j)
        uu[j] = *(const unsigned int*)(sp + (size_t)ed[j].x * NCLASS);
#pragma unroll
      for (int j = 0; j < 8; ++j) {
        int rel = it + 2 * j + half;
        float w = (rel < deg) ? __int_as_float(ed[j].y) : 0.0f;
        ax[j & 3] += w * __int_as_float(uu[j] << 16);
        ay[j & 3] += w * __int_as_float(uu[j] & 0xffff0000u);
      }
    }
  }
  float sx2 = (ax[0] + ax[1]) + (ax[2] + ax[3]);
  float sy2 = (ay[0] + ay[1]) + (ay[2] + ay[3]);
  sx2 += __shfl_xor(sx2, 32, 64);
  sy2 += __shfl_xor(sy2, 32, 64);
  float2 bv = *(const float2*)&bias[col];
  float vx = sx2 + bv.x, vy = sy2 + bv.y;

  bool valid = (hl < 20);
  float m = valid ? fmaxf(vx, vy) : -INFINITY;
#pragma unroll
  for (int d = 32; d; d >>= 1) m = fmaxf(m, __shfl_xor(m, d, 64));
  float ex = valid ? (expf(vx - m) + expf(vy - m)) : 0.0f;
  float s = ex;
#pragma unroll
  for (int d = 32; d; d >>= 1) s += __shfl_xor(s, d, 64);
  float ls = logf(s);
  if (half == 0 && valid)
    *(float2*)&out[(size_t)wid * NCLASS + hl * 2] = make_float2(vx - m - ls, vy - m - ls);
}

extern "C" void kernel_launch(void* const* d_in, const int* in_sizes, int n_in,
                              void* d_out, int out_size, void* d_ws, size_t ws_size,
                              hipStream_t stream) {
  const float* x   = (const float*)d_in[0];
  const int*   src = (const int*)d_in[1];
  const int*   dst = (const int*)d_in[2];
  const float* ew  = (const float*)d_in[3];
  const float* W[7]; const float* b[7];
  for (int i = 0; i < 7; ++i) {
    W[i] = (const float*)d_in[4 + 2 * i];
    b[i] = (const float*)d_in[5 + 2 * i];
  }
  int N = in_sizes[0] / NFEAT;   // 65536
  int E = in_sizes[1];           // 1048576

  char* ws = (char*)d_ws;
  int*      off     = (int*)(ws + 0);                 // (N+1) ints
  int*      bsum    = (int*)(ws + (1ll << 20));       // 256 ints
  int*      cnt     = (int*)(ws + (2ll << 20));       // N ints
  int2*     edata   = (int2*)(ws + (4ll << 20));      // E int2 = 8MB  [4,12)
  int*      rank    = (int*)(ws + (12ll << 20));      // E ints = 4MB  [12,16)
  ushort_t* support = (ushort_t*)(ws + (16ll << 20)); // N*64 bf16 = 8MB [16,24)
  float*    hA      = (float*)(ws + (32ll << 20));    // 16MB
  float*    hB      = (float*)(ws + (48ll << 20));    // 16MB

  // ---- build dst-CSR ----
  hipMemsetAsync(cnt, 0, (size_t)N * sizeof(int), stream);
  rank_k<<<(E / 4 + 255) / 256, 256, 0, stream>>>(dst, cnt, rank, E);
  int nb = (N + 255) / 256;  // 256 blocks
  scan1_k<<<nb, 256, 0, stream>>>(cnt, off, bsum, N);
  scan2_k<<<1, 256, 0, stream>>>(bsum, nb);
  scan3_k<<<nb, 256, 0, stream>>>(off, bsum, N, E);
  fill_k<<<(E + 255) / 256, 256, 0, stream>>>(src, dst, ew, off, rank, edata, E);

  int gb_gemm = N / 64;  // 1024 blocks
  int gb_agg  = N / 4;   // 4 waves per 256-thread block

  // L1: x[128] -> 64, relu
  gemm_k<128, 64><<<gb_gemm, 256, 0, stream>>>(x, W[0], support, N);
  agg_k<<<gb_agg, 256, 0, stream>>>(support, edata, off, b[0], nullptr, hA, N, 1);
  // L2
  gemm_k<64, 64><<<gb_gemm, 256, 0, stream>>>(hA, W[1], support, N);
  agg_k<<<gb_agg, 256, 0, stream>>>(support, edata, off, b[1], nullptr, hB, N, 1);
  // L3: + residual (h2 = hB)
  gemm_k<64, 64><<<gb_gemm, 256, 0, stream>>>(hB, W[2], support, N);
  agg_k<<<gb_agg, 256, 0, stream>>>(support, edata, off, b[2], hB, hA, N, 1);
  // L4: + residual (h3 = hA)
  gemm_k<64, 64><<<gb_gemm, 256, 0, stream>>>(hA, W[3], support, N);
  agg_k<<<gb_agg, 256, 0, stream>>>(support, edata, off, b[3], hA, hB, N, 1);
  // L5: + residual (h4 = hB)
  gemm_k<64, 64><<<gb_gemm, 256, 0, stream>>>(hB, W[4], support, N);
  agg_k<<<gb_agg, 256, 0, stream>>>(support, edata, off, b[4], hB, hA, N, 1);
  // L6
  gemm_k<64, 64><<<gb_gemm, 256, 0, stream>>>(hA, W[5], support, N);
  agg_k<<<gb_agg, 256, 0, stream>>>(support, edata, off, b[5], nullptr, hB, N, 1);
  // L7: 64 -> 40, + log_softmax
  gemm_k<64, 40><<<gb_gemm, 256, 0, stream>>>(hB, W[6], support, N);
  agg_final_k<<<gb_agg, 256, 0, stream>>>(support, edata, off, b[6], (float*)d_out, N);
}